// Round 12
// baseline (106.647 us; speedup 1.0000x reference)
//
#include <hip/hip_runtime.h>

// ---------- problem constants ----------
#define BB 4
#define WW 1024
#define CDIM 1024
#define CCH 32
#define NH 16
#define DH 64
#define MROWS (BB * WW)   // 4096

typedef __bf16 bf16x8 __attribute__((ext_vector_type(8)));
typedef float f32x4 __attribute__((ext_vector_type(4)));

static __device__ __forceinline__ unsigned short f2bf(float f) {
    union { float f; unsigned u; } v; v.f = f;
    unsigned r = v.u + 0x7fffu + ((v.u >> 16) & 1u);
    return (unsigned short)(r >> 16);
}

#if defined(__has_builtin)
#if __has_builtin(__builtin_amdgcn_global_load_lds)
#define HAVE_GLL 1
#endif
#endif

#ifdef HAVE_GLL
static __device__ __forceinline__ void gload16(const void* g, void* l) {
    __builtin_amdgcn_global_load_lds(
        (const __attribute__((address_space(1))) unsigned int*)g,
        (__attribute__((address_space(3))) unsigned int*)l, 16, 0, 0);
}
#endif

// ---------- kernel 1: fused weight-convert + pool (independent halves) ----------
__global__ __launch_bounds__(256) void prep_kernel(const float* __restrict__ aw,
                                                   const float* __restrict__ pw,
                                                   const float* __restrict__ x,
                                                   const float* __restrict__ pos,
                                                   const int* __restrict__ mask,
                                                   unsigned short* __restrict__ awb,
                                                   unsigned short* __restrict__ pwb,
                                                   float* __restrict__ word_f32,
                                                   unsigned short* __restrict__ word_bf) {
    int blk = blockIdx.x;
    if (blk < 4096) {
        int g = blk * 256 + threadIdx.x;          // 0 .. 1M-1
        const int NA4 = 3 * CDIM * CDIM / 4;      // 786432
        if (g < NA4) {
            float4 vv = ((const float4*)aw)[g];
            ushort4 o = { f2bf(vv.x), f2bf(vv.y), f2bf(vv.z), f2bf(vv.w) };
            ((ushort4*)awb)[g] = o;
        } else {
            int kk = g - NA4;
            float4 vv = ((const float4*)pw)[kk];
            ushort4 o = { f2bf(vv.x), f2bf(vv.y), f2bf(vv.z), f2bf(vv.w) };
            ((ushort4*)pwb)[kk] = o;
        }
    } else {
        int bw = blk - 4096;            // 0..4095
        int w = bw & (WW - 1);
        __shared__ int s_last;
        if (threadIdx.x == 0) {
            int ssum = 0;
            for (int j = 0; j < CCH; ++j) ssum += mask[bw * CCH + j];
            s_last = ssum - 1;          // may be -1 (one_hot(-1) == zeros)
        }
        __syncthreads();
        int last = s_last;
        const float4* xr = (const float4*)(x + ((size_t)bw * CCH + (last < 0 ? 0 : last)) * CDIM);
        const float4* pr = (const float4*)(pos + (size_t)w * CDIM);
        int d4 = threadIdx.x;
        float4 xv = (last >= 0) ? xr[d4] : float4{0.f, 0.f, 0.f, 0.f};
        float4 pv = pr[d4];
        float4 vv = { xv.x + pv.x, xv.y + pv.y, xv.z + pv.z, xv.w + pv.w };
        ((float4*)(word_f32 + (size_t)bw * CDIM))[d4] = vv;
        ushort4 o = { f2bf(vv.x), f2bf(vv.y), f2bf(vv.z), f2bf(vv.w) };
        ((ushort4*)(word_bf + (size_t)bw * CDIM))[d4] = o;
    }
}

// ---------- GEMM NT (m97 structure, 64KB-safe): C[m,n] = sum_k A[m,k]*Bt[n,k] ----------
// NW waves (NT = NW*64 threads). 1D grid, XCD-aware decomposition (NBX N-tiles,
// CW = NBX/8 per XCD). EPI 0: scatter qkv (q scaled 0.125); EPI 1: f32 store.
template <int EPI, int BM, int BN, int WRN, int WCN, int MI, int NI, int NBX, int CW>
__global__ __launch_bounds__(WRN * WCN * 64) void gemm_nt_kernel(
        const unsigned short* __restrict__ A,
        const unsigned short* __restrict__ Bt,
        int Mdim, int Ndim, int Kdim,
        unsigned short* __restrict__ qb,
        unsigned short* __restrict__ kb,
        unsigned short* __restrict__ vb,
        float* __restrict__ outp) {
    const int NW = WRN * WCN;
    const int NT = NW * 64;
    __shared__ unsigned short As[BM * 64];
    __shared__ unsigned short Bs[BN * 64];
    int t = threadIdx.x;
    int wid = t >> 6, lane = t & 63;
    int wr = wid / WCN, wc = wid % WCN;
    int bid = blockIdx.x;
    int xcd = bid & 7, idx = bid >> 3;
    int bx = xcd * CW + idx % CW;
    int by = idx / CW;
    int mbase = by * BM, nbase = bx * BN;
    int lr = lane & 15, lg = lane >> 4;
    f32x4 acc[MI][NI] = {};

#ifdef HAVE_GLL
    int csrc = ((lane & 7) ^ (lane >> 3)) * 8;   // pre-swizzled source column
    int rofs = lane >> 3;
    const int TOT = (BM + BN) / 8;               // 8-row chunks of 64 cols (1 KB each)
#endif

    for (int kt = 0; kt < Kdim; kt += 64) {
        __syncthreads();
#ifdef HAVE_GLL
        for (int cch = wid; cch < TOT; cch += NW) {
            if (cch < BM / 8)
                gload16(A + (size_t)(mbase + cch * 8 + rofs) * Kdim + kt + csrc, &As[cch * 8 * 64]);
            else {
                int cb = cch - BM / 8;
                gload16(Bt + (size_t)(nbase + cb * 8 + rofs) * Kdim + kt + csrc, &Bs[cb * 8 * 64]);
            }
        }
#else
        for (int s = 0; s < (BM + BN) * 8 / NT; ++s) {
            int f = s * NT + t;
            int row = f >> 3, c8 = (f & 7) * 8;
            if (row < BM)
                *(int4*)&As[row * 64 + (c8 ^ ((row & 7) << 3))] =
                    *(const int4*)&A[(size_t)(mbase + row) * Kdim + kt + c8];
            else {
                int rb = row - BM;
                *(int4*)&Bs[rb * 64 + (c8 ^ ((rb & 7) << 3))] =
                    *(const int4*)&Bt[(size_t)(nbase + rb) * Kdim + kt + c8];
            }
        }
#endif
        __syncthreads();
        for (int ks = 0; ks < 2; ++ks) {
            bf16x8 af[MI], bfr[NI];
            int cc = ks * 32 + lg * 8;
            for (int mi = 0; mi < MI; ++mi) {
                int r = wr * (MI * 16) + mi * 16 + lr;
                af[mi] = *(const bf16x8*)&As[r * 64 + (cc ^ ((r & 7) << 3))];
            }
            for (int ni = 0; ni < NI; ++ni) {
                int r = wc * (NI * 16) + ni * 16 + lr;
                bfr[ni] = *(const bf16x8*)&Bs[r * 64 + (cc ^ ((r & 7) << 3))];
            }
            __builtin_amdgcn_s_setprio(1);
            for (int mi = 0; mi < MI; ++mi)
                for (int ni = 0; ni < NI; ++ni)
                    acc[mi][ni] = __builtin_amdgcn_mfma_f32_16x16x32_bf16(af[mi], bfr[ni], acc[mi][ni], 0, 0, 0);
            __builtin_amdgcn_s_setprio(0);
        }
    }
    for (int mi = 0; mi < MI; ++mi)
        for (int ni = 0; ni < NI; ++ni)
            for (int i = 0; i < 4; ++i) {
                int row = mbase + wr * (MI * 16) + mi * 16 + lg * 4 + i;
                int col = nbase + wc * (NI * 16) + ni * 16 + lr;
                float v = acc[mi][ni][i];
                if (EPI == 0) {
                    int sect = col >> 10, ch = col & 1023, hh = ch >> 6, dd = ch & 63;
                    int bI = row >> 10, wI = row & 1023;
                    size_t dst = ((size_t)(bI * NH + hh) * WW + wI) * DH + dd;
                    if (sect == 0) qb[dst] = f2bf(v * 0.125f);
                    else if (sect == 1) kb[dst] = f2bf(v);
                    else vb[dst] = f2bf(v);
                } else {
                    outp[(size_t)row * Ndim + col] = v;
                }
            }
}

// ---------- kernel 4: causal flash attention, dual 64-row q-tiles, 2 blocks/CU ----------
// grid 512 (1D), 256 threads (4 waves, 16 rows per tile each).
// Block p in 0..7 handles q-tiles p and 15-p: exactly 17 kv-units of compute.
// XCD remap: all 8 blocks of a (b,h) on one XCD (K/V 256KB L2-resident).
// Static-shift softmax (no max-reduce, deferred row-sum); Ps wave-private.
__global__ __launch_bounds__(256) void attn_kernel(const unsigned short* __restrict__ q,
                                                   const unsigned short* __restrict__ k,
                                                   const unsigned short* __restrict__ v,
                                                   unsigned short* __restrict__ aout) {
    __shared__ unsigned short Ks[64 * 64];
    __shared__ unsigned short Vt[64 * 64];      // transposed: Vt[d][kv]
    __shared__ unsigned short Ps0[64 * 64];
    __shared__ unsigned short Ps1[64 * 64];
    int t = threadIdx.x;
    int wid = t >> 6, lane = t & 63;
    int lr = lane & 15, lg = lane >> 4;
    // remap: bid -> (bh, p); 8 p-blocks of a bh stay on one XCD
    int bid = blockIdx.x;
    int xcd = bid & 7, idx = bid >> 3;          // idx 0..63
    int bh = xcd + ((idx >> 3) << 3);           // 0..63
    int p = idx & 7;                            // 0..7
    int bI = bh >> 4, hI = bh & 15;
    int qa = p * 64, qbv = (15 - p) * 64;
    int nktA = p + 1, nktB = 16 - p;
    const float EXP2C = 1.44269504f;             // log2(e)
    const float SHIFTC = 28.8539008f;            // 20 * log2(e)

    bf16x8 qfA[2], qfB[2];
    {
        const unsigned short* qg = q + (size_t)bh * WW * DH;
        int r = wid * 16 + lr;
        for (int ks = 0; ks < 2; ++ks) {
            qfA[ks] = *(const bf16x8*)&qg[(size_t)(qa + r) * DH + ks * 32 + lg * 8];
            qfB[ks] = *(const bf16x8*)&qg[(size_t)(qbv + r) * DH + ks * 32 + lg * 8];
        }
    }

    float rlA[4] = {0.f, 0.f, 0.f, 0.f}, rlB[4] = {0.f, 0.f, 0.f, 0.f};
    f32x4 oA[4] = {}, oB[4] = {};

    const unsigned short* kbase = k + (size_t)bh * WW * DH;
    const unsigned short* vbase = v + (size_t)bh * WW * DH;
    // staging split: waves 0-1 transpose V (32 elems/thread), waves 2-3 load K
    int dp = (t & 31) * 2, kb4 = (t >> 5) & 3;   // V mapping (wid<2)
    int tt = t & 127;                            // K mapping (wid>=2)
    int krow = tt >> 1, kcb = (tt & 1) * 32;

    unsigned int vr[16]; int4 kr[4];
    auto prefetch = [&](int tn) {
        if (wid < 2) {
            const unsigned short* vg = vbase + (size_t)tn * 64 * DH;
#pragma unroll
            for (int j = 0; j < 16; ++j)
                vr[j] = *(const unsigned int*)&vg[(size_t)(kb4 * 16 + j) * DH + dp];
        } else {
            const unsigned short* kg = kbase + (size_t)tn * 64 * DH;
#pragma unroll
            for (int j = 0; j < 4; ++j)
                kr[j] = *(const int4*)&kg[(size_t)krow * DH + kcb + j * 8];
        }
    };
    prefetch(0);

    // QK^T (shared K-frags) -> static-shift exp -> partial row sums -> P to LDS
    auto process = [&](const bf16x8* qf, const bf16x8 (*bfr)[4], int qbase,
                       float* rl, unsigned short* PsX, int tki) {
        f32x4 s[4] = {};
        __builtin_amdgcn_s_setprio(1);
#pragma unroll
        for (int ks = 0; ks < 2; ++ks)
#pragma unroll
            for (int ni = 0; ni < 4; ++ni)
                s[ni] = __builtin_amdgcn_mfma_f32_16x16x32_bf16(qf[ks], bfr[ks][ni], s[ni], 0, 0, 0);
        __builtin_amdgcn_s_setprio(0);
        int rowbase = qbase + wid * 16 + lg * 4;
        if (tki * 64 + 63 > qbase + wid * 16) {
            for (int ni = 0; ni < 4; ++ni)
                for (int i = 0; i < 4; ++i) {
                    int ki = tki * 64 + ni * 16 + lr;
                    if (ki > rowbase + i) s[ni][i] = -1e30f;
                }
        }
#pragma unroll
        for (int ni = 0; ni < 4; ++ni)
#pragma unroll
            for (int i = 0; i < 4; ++i) {
                float pe = __builtin_amdgcn_exp2f(fmaf(s[ni][i], EXP2C, -SHIFTC));
                s[ni][i] = pe;
                rl[i] += pe;
            }
        for (int ni = 0; ni < 4; ++ni)
            for (int i = 0; i < 4; ++i) {
                int r = wid * 16 + lg * 4 + i;
                PsX[r * 64 + ((ni * 16 + lr) ^ ((r & 7) << 3))] = f2bf(s[ni][i]);
            }
    };

    auto pvacc = [&](f32x4* o, const unsigned short* PsX, const bf16x8 (*vbf)[4]) {
#pragma unroll
        for (int ks = 0; ks < 2; ++ks) {
            int cc = ks * 32 + lg * 8;
            int r = wid * 16 + lr;
            bf16x8 pa = *(const bf16x8*)&PsX[r * 64 + (cc ^ ((r & 7) << 3))];
            __builtin_amdgcn_s_setprio(1);
#pragma unroll
            for (int di = 0; di < 4; ++di)
                o[di] = __builtin_amdgcn_mfma_f32_16x16x32_bf16(pa, vbf[ks][di], o[di], 0, 0, 0);
            __builtin_amdgcn_s_setprio(0);
        }
    };

    for (int tki = 0; tki < nktB; ++tki) {
        __syncthreads();   // prev iter's Ks/Vt reads complete
        if (wid < 2) {
            unsigned short lo[16], hi[16];
#pragma unroll
            for (int j = 0; j < 16; ++j) { lo[j] = (unsigned short)(vr[j] & 0xffffu);
                                           hi[j] = (unsigned short)(vr[j] >> 16); }
            *(int4*)&Vt[dp * 64 + ((kb4 * 16) ^ ((dp & 7) << 3))] = *(int4*)&lo[0];
            *(int4*)&Vt[dp * 64 + ((kb4 * 16 + 8) ^ ((dp & 7) << 3))] = *(int4*)&lo[8];
            int d1 = dp + 1;
            *(int4*)&Vt[d1 * 64 + ((kb4 * 16) ^ ((d1 & 7) << 3))] = *(int4*)&hi[0];
            *(int4*)&Vt[d1 * 64 + ((kb4 * 16 + 8) ^ ((d1 & 7) << 3))] = *(int4*)&hi[8];
        } else {
#pragma unroll
            for (int j = 0; j < 4; ++j)
                *(int4*)&Ks[krow * 64 + ((kcb + j * 8) ^ ((krow & 7) << 3))] = kr[j];
        }
        if (tki + 1 < nktB) prefetch(tki + 1);   // loads fly under compute
        __syncthreads();

        bool wB = (tki * 64 <= qbv + wid * 16 + 15);   // wave-level diagonal skip
        bool wA = (tki < nktA) && (tki * 64 <= qa + wid * 16 + 15);

        bf16x8 bfr[2][4];                               // hoisted K-frags (shared)
#pragma unroll
        for (int ks = 0; ks < 2; ++ks) {
            int cc = ks * 32 + lg * 8;
#pragma unroll
            for (int ni = 0; ni < 4; ++ni) {
                int r = ni * 16 + lr;
                bfr[ks][ni] = *(const bf16x8*)&Ks[r * 64 + (cc ^ ((r & 7) << 3))];
            }
        }
        if (wB) process(qfB, bfr, qbv, rlB, Ps1, tki);
        if (wA) process(qfA, bfr, qa, rlA, Ps0, tki);

        bf16x8 vbf[2][4];                               // hoisted V-frags (shared)
#pragma unroll
        for (int ks = 0; ks < 2; ++ks) {
            int cc = ks * 32 + lg * 8;
#pragma unroll
            for (int di = 0; di < 4; ++di) {
                int rv = di * 16 + lr;
                vbf[ks][di] = *(const bf16x8*)&Vt[rv * 64 + (cc ^ ((rv & 7) << 3))];
            }
        }
        // no barrier: Ps rows are wave-private (written+read by the same wave)
        if (wB) pvacc(oB, Ps1, vbf);
        if (wA) pvacc(oA, Ps0, vbf);
    }

    // epilogue: one row-sum reduce + reciprocal per row, then store
    float riA[4], riB[4];
#pragma unroll
    for (int i = 0; i < 4; ++i) {
        for (int d = 8; d >= 1; d >>= 1) rlA[i] += __shfl_xor(rlA[i], d);
        for (int d = 8; d >= 1; d >>= 1) rlB[i] += __shfl_xor(rlB[i], d);
        riA[i] = 1.0f / rlA[i];
        riB[i] = 1.0f / rlB[i];
    }
    for (int di = 0; di < 4; ++di)
        for (int i = 0; i < 4; ++i) {
            int dd = di * 16 + lr;
            int qrA = qa + wid * 16 + lg * 4 + i;
            int qrB = qbv + wid * 16 + lg * 4 + i;
            aout[((size_t)bI * WW + qrA) * CDIM + hI * DH + dd] = f2bf(oA[di][i] * riA[i]);
            aout[((size_t)bI * WW + qrB) * CDIM + hI * DH + dd] = f2bf(oB[di][i] * riB[i]);
        }
}

// ---------- launch ----------
extern "C" void kernel_launch(void* const* d_in, const int* in_sizes, int n_in,
                              void* d_out, int out_size, void* d_ws, size_t ws_size,
                              hipStream_t stream) {
    const float* x    = (const float*)d_in[0];
    const float* pos  = (const float*)d_in[1];
    const float* aw   = (const float*)d_in[2];
    const float* pw   = (const float*)d_in[3];
    const int*   mask = (const int*)d_in[4];
    float* out = (float*)d_out;
    float* word_f32 = out;                        // [4096,1024] f32
    float* proj_out = out + (size_t)MROWS * CDIM; // [4096,1024] f32

    const size_t MB = 1u << 20;
    char* ws = (char*)d_ws;
    unsigned short* word_bf = (unsigned short*)(ws);             // 8 MB
    unsigned short* awb     = (unsigned short*)(ws + 8 * MB);    // 6 MB
    unsigned short* pwb     = (unsigned short*)(ws + 14 * MB);   // 2 MB
    unsigned short* qb      = (unsigned short*)(ws + 16 * MB);   // 8 MB
    unsigned short* kb      = (unsigned short*)(ws + 24 * MB);   // 8 MB
    unsigned short* vb      = (unsigned short*)(ws + 32 * MB);   // 8 MB
    unsigned short* aob     = (unsigned short*)(ws + 40 * MB);   // 8 MB

    prep_kernel<<<8192, 256, 0, stream>>>(aw, pw, x, pos, mask, awb, pwb, word_f32, word_bf);
    // QKV: M=4096, N=3072, K=1024; 128x128 tiles, 256 thr; grid 768 (24 N x 32 M), CW=3
    gemm_nt_kernel<0, 128, 128, 2, 2, 4, 4, 24, 3><<<768, 256, 0, stream>>>(
        word_bf, awb, MROWS, 3 * CDIM, CDIM, qb, kb, vb, nullptr);
    // attention: dual 64-row q-tiles; grid 512 (2 blocks/CU), 256 threads
    attn_kernel<<<512, 256, 0, stream>>>(qb, kb, vb, aob);
    // proj: M=4096, N=1024, K=1024; 128x64 tiles, 256 thr; grid 512 (16 N x 32 M), CW=2
    gemm_nt_kernel<1, 128, 64, 4, 1, 2, 4, 16, 2><<<512, 256, 0, stream>>>(
        aob, pwb, MROWS, CDIM, CDIM, nullptr, nullptr, nullptr, proj_out);
}

// Round 13
// 98.625 us; speedup vs baseline: 1.0813x; 1.0813x over previous
//
#include <hip/hip_runtime.h>

// ---------- problem constants ----------
#define BB 4
#define WW 1024
#define CDIM 1024
#define CCH 32
#define NH 16
#define DH 64
#define MROWS (BB * WW)   // 4096

typedef __bf16 bf16x8 __attribute__((ext_vector_type(8)));
typedef float f32x4 __attribute__((ext_vector_type(4)));

static __device__ __forceinline__ unsigned short f2bf(float f) {
    union { float f; unsigned u; } v; v.f = f;
    unsigned r = v.u + 0x7fffu + ((v.u >> 16) & 1u);
    return (unsigned short)(r >> 16);
}

#if defined(__has_builtin)
#if __has_builtin(__builtin_amdgcn_global_load_lds)
#define HAVE_GLL 1
#endif
#endif

#ifdef HAVE_GLL
static __device__ __forceinline__ void gload16(const void* g, void* l) {
    __builtin_amdgcn_global_load_lds(
        (const __attribute__((address_space(1))) unsigned int*)g,
        (__attribute__((address_space(3))) unsigned int*)l, 16, 0, 0);
}
#endif

// ---------- kernel 1: fused weight-convert + pool (independent halves) ----------
__global__ __launch_bounds__(256) void prep_kernel(const float* __restrict__ aw,
                                                   const float* __restrict__ pw,
                                                   const float* __restrict__ x,
                                                   const float* __restrict__ pos,
                                                   const int* __restrict__ mask,
                                                   unsigned short* __restrict__ awb,
                                                   unsigned short* __restrict__ pwb,
                                                   float* __restrict__ word_f32,
                                                   unsigned short* __restrict__ word_bf) {
    int blk = blockIdx.x;
    if (blk < 4096) {
        int g = blk * 256 + threadIdx.x;          // 0 .. 1M-1
        const int NA4 = 3 * CDIM * CDIM / 4;      // 786432
        if (g < NA4) {
            float4 vv = ((const float4*)aw)[g];
            ushort4 o = { f2bf(vv.x), f2bf(vv.y), f2bf(vv.z), f2bf(vv.w) };
            ((ushort4*)awb)[g] = o;
        } else {
            int kk = g - NA4;
            float4 vv = ((const float4*)pw)[kk];
            ushort4 o = { f2bf(vv.x), f2bf(vv.y), f2bf(vv.z), f2bf(vv.w) };
            ((ushort4*)pwb)[kk] = o;
        }
    } else {
        int bw = blk - 4096;            // 0..4095
        int w = bw & (WW - 1);
        __shared__ int s_last;
        if (threadIdx.x == 0) {
            int ssum = 0;
            for (int j = 0; j < CCH; ++j) ssum += mask[bw * CCH + j];
            s_last = ssum - 1;          // may be -1 (one_hot(-1) == zeros)
        }
        __syncthreads();
        int last = s_last;
        const float4* xr = (const float4*)(x + ((size_t)bw * CCH + (last < 0 ? 0 : last)) * CDIM);
        const float4* pr = (const float4*)(pos + (size_t)w * CDIM);
        int d4 = threadIdx.x;
        float4 xv = (last >= 0) ? xr[d4] : float4{0.f, 0.f, 0.f, 0.f};
        float4 pv = pr[d4];
        float4 vv = { xv.x + pv.x, xv.y + pv.y, xv.z + pv.z, xv.w + pv.w };
        ((float4*)(word_f32 + (size_t)bw * CDIM))[d4] = vv;
        ushort4 o = { f2bf(vv.x), f2bf(vv.y), f2bf(vv.z), f2bf(vv.w) };
        ((ushort4*)(word_bf + (size_t)bw * CDIM))[d4] = o;
    }
}

// ---------- GEMM NT (m97 structure, 64KB-safe): C[m,n] = sum_k A[m,k]*Bt[n,k] ----------
// NW waves. 1D grid, XCD-aware decomposition (NBX N-tiles, CW = NBX/8 per XCD).
// Epilogue restages acc through LDS for fully-coalesced int4/float4 stores.
// EPI 0: scatter qkv (q scaled 0.125) bf16; EPI 1: f32 store to outp.
template <int EPI, int BM, int BN, int WRN, int WCN, int MI, int NI, int NBX, int CW>
__global__ __launch_bounds__(WRN * WCN * 64) void gemm_nt_kernel(
        const unsigned short* __restrict__ A,
        const unsigned short* __restrict__ Bt,
        int Mdim, int Ndim, int Kdim,
        unsigned short* __restrict__ qb,
        unsigned short* __restrict__ kb,
        unsigned short* __restrict__ vb,
        float* __restrict__ outp) {
    const int NW = WRN * WCN;
    const int NT = NW * 64;
    __shared__ unsigned short SMEM[(BM + BN) * 64];
    unsigned short* As = SMEM;
    unsigned short* Bs = SMEM + BM * 64;
    int t = threadIdx.x;
    int wid = t >> 6, lane = t & 63;
    int wr = wid / WCN, wc = wid % WCN;
    int bid = blockIdx.x;
    int xcd = bid & 7, idx = bid >> 3;
    int bx = xcd * CW + idx % CW;
    int by = idx / CW;
    int mbase = by * BM, nbase = bx * BN;
    int lr = lane & 15, lg = lane >> 4;
    f32x4 acc[MI][NI] = {};

#ifdef HAVE_GLL
    int csrc = ((lane & 7) ^ (lane >> 3)) * 8;   // pre-swizzled source column
    int rofs = lane >> 3;
    const int TOT = (BM + BN) / 8;               // 8-row chunks of 64 cols (1 KB each)
#endif

    for (int kt = 0; kt < Kdim; kt += 64) {
        __syncthreads();
#ifdef HAVE_GLL
        for (int cch = wid; cch < TOT; cch += NW) {
            if (cch < BM / 8)
                gload16(A + (size_t)(mbase + cch * 8 + rofs) * Kdim + kt + csrc, &As[cch * 8 * 64]);
            else {
                int cb = cch - BM / 8;
                gload16(Bt + (size_t)(nbase + cb * 8 + rofs) * Kdim + kt + csrc, &Bs[cb * 8 * 64]);
            }
        }
#else
        for (int s = 0; s < (BM + BN) * 8 / NT; ++s) {
            int f = s * NT + t;
            int row = f >> 3, c8 = (f & 7) * 8;
            if (row < BM)
                *(int4*)&As[row * 64 + (c8 ^ ((row & 7) << 3))] =
                    *(const int4*)&A[(size_t)(mbase + row) * Kdim + kt + c8];
            else {
                int rb = row - BM;
                *(int4*)&Bs[rb * 64 + (c8 ^ ((rb & 7) << 3))] =
                    *(const int4*)&Bt[(size_t)(nbase + rb) * Kdim + kt + c8];
            }
        }
#endif
        __syncthreads();
        for (int ks = 0; ks < 2; ++ks) {
            bf16x8 af[MI], bfr[NI];
            int cc = ks * 32 + lg * 8;
            for (int mi = 0; mi < MI; ++mi) {
                int r = wr * (MI * 16) + mi * 16 + lr;
                af[mi] = *(const bf16x8*)&As[r * 64 + (cc ^ ((r & 7) << 3))];
            }
            for (int ni = 0; ni < NI; ++ni) {
                int r = wc * (NI * 16) + ni * 16 + lr;
                bfr[ni] = *(const bf16x8*)&Bs[r * 64 + (cc ^ ((r & 7) << 3))];
            }
            __builtin_amdgcn_s_setprio(1);
            for (int mi = 0; mi < MI; ++mi)
                for (int ni = 0; ni < NI; ++ni)
                    acc[mi][ni] = __builtin_amdgcn_mfma_f32_16x16x32_bf16(af[mi], bfr[ni], acc[mi][ni], 0, 0, 0);
            __builtin_amdgcn_s_setprio(0);
        }
    }

    // ---- vectorized epilogue: restage acc (per mi band) through LDS ----
    const int PITCH = BN + 4;
    float* Ls = (float*)SMEM;       // (WRN*16) x PITCH f32 per band
    const int CPR = BN / 16;        // 16-f32 chunks per row
    int erow = t / CPR, ech = t % CPR;
    int grow_base = mbase + (erow >> 4) * (MI * 16) + (erow & 15);
    __syncthreads();                // all frag reads done before SMEM reuse
    for (int mi = 0; mi < MI; ++mi) {
        for (int ni = 0; ni < NI; ++ni)
            for (int i = 0; i < 4; ++i)
                Ls[(wr * 16 + lg * 4 + i) * PITCH + wc * (NI * 16) + ni * 16 + lr] = acc[mi][ni][i];
        __syncthreads();
        float vv[16];
        for (int j4 = 0; j4 < 4; ++j4)
            *(float4*)&vv[j4 * 4] = *(const float4*)&Ls[erow * PITCH + ech * 16 + j4 * 4];
        int grow = grow_base + mi * 16;
        int gcol = nbase + ech * 16;
        if (EPI == 0) {
            int sect = gcol >> 10, hh = (gcol & 1023) >> 6, dd0 = gcol & 63;
            int bI = grow >> 10, wI = grow & 1023;
            size_t dst = ((size_t)(bI * NH + hh) * WW + wI) * DH + dd0;
            float scl = (sect == 0) ? 0.125f : 1.0f;   // fold softmax scale into q (exact pow2)
            unsigned short ob[16];
            for (int j = 0; j < 16; ++j) ob[j] = f2bf(vv[j] * scl);
            unsigned short* bdst = (sect == 0) ? qb : (sect == 1) ? kb : vb;
            *(int4*)&bdst[dst] = *(const int4*)&ob[0];
            *(int4*)&bdst[dst + 8] = *(const int4*)&ob[8];
        } else {
            float* po = &outp[(size_t)grow * Ndim + gcol];
            for (int j4 = 0; j4 < 4; ++j4)
                *(float4*)&po[j4 * 4] = *(const float4*)&vv[j4 * 4];
        }
        __syncthreads();            // band consumed before next overwrite
    }
}

// ---------- kernel 4: causal flash attention (r10 structure, proven best) ----------
// 1D grid 256, 512 threads (8 waves, 16 rows per tile each). Block p handles
// q-tiles p and 7-p (18 kv-units). XCD remap co-locates a (b,h)'s 4 blocks.
// Static-shift softmax (no max-reduce, deferred row-sum); Ps wave-private.
__global__ __launch_bounds__(512) void attn_kernel(const unsigned short* __restrict__ q,
                                                   const unsigned short* __restrict__ k,
                                                   const unsigned short* __restrict__ v,
                                                   unsigned short* __restrict__ aout) {
    __shared__ unsigned short Ks[64 * 64];
    __shared__ unsigned short Vt[64 * 64];      // transposed: Vt[d][kv]
    __shared__ unsigned short Ps0[128 * 64];
    __shared__ unsigned short Ps1[128 * 64];
    int t = threadIdx.x;
    int wid = t >> 6, lane = t & 63;
    int lr = lane & 15, lg = lane >> 4;
    int bid = blockIdx.x;
    int xcd = bid & 7, idx = bid >> 3;          // idx 0..31
    int bh = xcd + ((idx >> 2) << 3);           // 0..63
    int p = idx & 3;                            // 0..3
    int bI = bh >> 4, hI = bh & 15;
    int qa = p * 128, qbv = (7 - p) * 128;
    int nktA = 2 * p + 2, nktB = 16 - 2 * p;
    const float EXP2C = 1.44269504f;             // log2(e)
    const float SHIFTC = 28.8539008f;            // 20 * log2(e)

    bf16x8 qfA[2], qfB[2];
    {
        const unsigned short* qg = q + (size_t)bh * WW * DH;
        int r = wid * 16 + lr;
        for (int ks = 0; ks < 2; ++ks) {
            qfA[ks] = *(const bf16x8*)&qg[(size_t)(qa + r) * DH + ks * 32 + lg * 8];
            qfB[ks] = *(const bf16x8*)&qg[(size_t)(qbv + r) * DH + ks * 32 + lg * 8];
        }
    }

    float rlA[4] = {0.f, 0.f, 0.f, 0.f}, rlB[4] = {0.f, 0.f, 0.f, 0.f};
    f32x4 oA[4] = {}, oB[4] = {};

    const unsigned short* kbase = k + (size_t)bh * WW * DH;
    const unsigned short* vbase = v + (size_t)bh * WW * DH;
    int dp = (t & 31) * 2, kb8 = (t >> 5) & 7;
    int tt = t & 255;
    int krow = tt >> 3, kc8 = (tt & 7) * 8;

    unsigned int vr[8]; int4 kr0, kr1;
    auto prefetch = [&](int tn) {
        if (wid < 4) {
            const unsigned short* vg = vbase + (size_t)tn * 64 * DH;
#pragma unroll
            for (int j = 0; j < 8; ++j)
                vr[j] = *(const unsigned int*)&vg[(size_t)(kb8 * 8 + j) * DH + dp];
        } else {
            const unsigned short* kg = kbase + (size_t)tn * 64 * DH;
            kr0 = *(const int4*)&kg[(size_t)krow * DH + kc8];
            kr1 = *(const int4*)&kg[(size_t)(krow + 32) * DH + kc8];
        }
    };
    prefetch(0);

    auto process = [&](const bf16x8* qf, const bf16x8 (*bfr)[4], int qbase,
                       float* rl, unsigned short* PsX, int tki) {
        f32x4 s[4] = {};
        __builtin_amdgcn_s_setprio(1);
#pragma unroll
        for (int ks = 0; ks < 2; ++ks)
#pragma unroll
            for (int ni = 0; ni < 4; ++ni)
                s[ni] = __builtin_amdgcn_mfma_f32_16x16x32_bf16(qf[ks], bfr[ks][ni], s[ni], 0, 0, 0);
        __builtin_amdgcn_s_setprio(0);
        int rowbase = qbase + wid * 16 + lg * 4;
        if (tki * 64 + 63 > qbase + wid * 16) {
            for (int ni = 0; ni < 4; ++ni)
                for (int i = 0; i < 4; ++i) {
                    int ki = tki * 64 + ni * 16 + lr;
                    if (ki > rowbase + i) s[ni][i] = -1e30f;
                }
        }
#pragma unroll
        for (int ni = 0; ni < 4; ++ni)
#pragma unroll
            for (int i = 0; i < 4; ++i) {
                float pe = __builtin_amdgcn_exp2f(fmaf(s[ni][i], EXP2C, -SHIFTC));
                s[ni][i] = pe;
                rl[i] += pe;
            }
        for (int ni = 0; ni < 4; ++ni)
            for (int i = 0; i < 4; ++i) {
                int r = wid * 16 + lg * 4 + i;
                PsX[r * 64 + ((ni * 16 + lr) ^ ((r & 7) << 3))] = f2bf(s[ni][i]);
            }
    };

    auto pvacc = [&](f32x4* o, const unsigned short* PsX, const bf16x8 (*vbf)[4]) {
#pragma unroll
        for (int ks = 0; ks < 2; ++ks) {
            int cc = ks * 32 + lg * 8;
            int r = wid * 16 + lr;
            bf16x8 pa = *(const bf16x8*)&PsX[r * 64 + (cc ^ ((r & 7) << 3))];
            __builtin_amdgcn_s_setprio(1);
#pragma unroll
            for (int di = 0; di < 4; ++di)
                o[di] = __builtin_amdgcn_mfma_f32_16x16x32_bf16(pa, vbf[ks][di], o[di], 0, 0, 0);
            __builtin_amdgcn_s_setprio(0);
        }
    };

    for (int tki = 0; tki < nktB; ++tki) {
        __syncthreads();   // prev iter's Ks/Vt reads complete
        if (wid < 4) {
            unsigned short lo[8], hi[8];
#pragma unroll
            for (int j = 0; j < 8; ++j) { lo[j] = (unsigned short)(vr[j] & 0xffffu);
                                          hi[j] = (unsigned short)(vr[j] >> 16); }
            *(int4*)&Vt[dp * 64 + ((kb8 * 8) ^ ((dp & 7) << 3))] = *(int4*)lo;
            int d1 = dp + 1;
            *(int4*)&Vt[d1 * 64 + ((kb8 * 8) ^ ((d1 & 7) << 3))] = *(int4*)hi;
        } else {
            *(int4*)&Ks[krow * 64 + (kc8 ^ ((krow & 7) << 3))] = kr0;
            int r1 = krow + 32;
            *(int4*)&Ks[r1 * 64 + (kc8 ^ ((r1 & 7) << 3))] = kr1;
        }
        if (tki + 1 < nktB) prefetch(tki + 1);   // loads fly under compute
        __syncthreads();

        bool wB = (tki * 64 <= qbv + wid * 16 + 15);   // wave-level diagonal skip
        bool wA = (tki < nktA) && (tki * 64 <= qa + wid * 16 + 15);

        bf16x8 bfr[2][4];                               // hoisted K-frags (shared)
#pragma unroll
        for (int ks = 0; ks < 2; ++ks) {
            int cc = ks * 32 + lg * 8;
#pragma unroll
            for (int ni = 0; ni < 4; ++ni) {
                int r = ni * 16 + lr;
                bfr[ks][ni] = *(const bf16x8*)&Ks[r * 64 + (cc ^ ((r & 7) << 3))];
            }
        }
        if (wB) process(qfB, bfr, qbv, rlB, Ps1, tki);
        if (wA) process(qfA, bfr, qa, rlA, Ps0, tki);

        bf16x8 vbf[2][4];                               // hoisted V-frags (shared)
#pragma unroll
        for (int ks = 0; ks < 2; ++ks) {
            int cc = ks * 32 + lg * 8;
#pragma unroll
            for (int di = 0; di < 4; ++di) {
                int rv = di * 16 + lr;
                vbf[ks][di] = *(const bf16x8*)&Vt[rv * 64 + (cc ^ ((rv & 7) << 3))];
            }
        }
        // no barrier: Ps rows are wave-private (written+read by the same wave)
        if (wB) pvacc(oB, Ps1, vbf);
        if (wA) pvacc(oA, Ps0, vbf);
    }

    // epilogue: one row-sum reduce + reciprocal per row, then store
    float riA[4], riB[4];
#pragma unroll
    for (int i = 0; i < 4; ++i) {
        for (int d = 8; d >= 1; d >>= 1) rlA[i] += __shfl_xor(rlA[i], d);
        for (int d = 8; d >= 1; d >>= 1) rlB[i] += __shfl_xor(rlB[i], d);
        riA[i] = 1.0f / rlA[i];
        riB[i] = 1.0f / rlB[i];
    }
    for (int di = 0; di < 4; ++di)
        for (int i = 0; i < 4; ++i) {
            int dd = di * 16 + lr;
            int qrA = qa + wid * 16 + lg * 4 + i;
            int qrB = qbv + wid * 16 + lg * 4 + i;
            aout[((size_t)bI * WW + qrA) * CDIM + hI * DH + dd] = f2bf(oA[di][i] * riA[i]);
            aout[((size_t)bI * WW + qrB) * CDIM + hI * DH + dd] = f2bf(oB[di][i] * riB[i]);
        }
}

// ---------- launch ----------
extern "C" void kernel_launch(void* const* d_in, const int* in_sizes, int n_in,
                              void* d_out, int out_size, void* d_ws, size_t ws_size,
                              hipStream_t stream) {
    const float* x    = (const float*)d_in[0];
    const float* pos  = (const float*)d_in[1];
    const float* aw   = (const float*)d_in[2];
    const float* pw   = (const float*)d_in[3];
    const int*   mask = (const int*)d_in[4];
    float* out = (float*)d_out;
    float* word_f32 = out;                        // [4096,1024] f32
    float* proj_out = out + (size_t)MROWS * CDIM; // [4096,1024] f32

    const size_t MB = 1u << 20;
    char* ws = (char*)d_ws;
    unsigned short* word_bf = (unsigned short*)(ws);             // 8 MB
    unsigned short* awb     = (unsigned short*)(ws + 8 * MB);    // 6 MB
    unsigned short* pwb     = (unsigned short*)(ws + 14 * MB);   // 2 MB
    unsigned short* qb      = (unsigned short*)(ws + 16 * MB);   // 8 MB
    unsigned short* kb      = (unsigned short*)(ws + 24 * MB);   // 8 MB
    unsigned short* vb      = (unsigned short*)(ws + 32 * MB);   // 8 MB
    unsigned short* aob     = (unsigned short*)(ws + 40 * MB);   // 8 MB

    prep_kernel<<<8192, 256, 0, stream>>>(aw, pw, x, pos, mask, awb, pwb, word_f32, word_bf);
    // QKV: M=4096, N=3072, K=1024; 128x128 tiles, 256 thr; grid 768 (24 N x 32 M), CW=3
    gemm_nt_kernel<0, 128, 128, 2, 2, 4, 4, 24, 3><<<768, 256, 0, stream>>>(
        word_bf, awb, MROWS, 3 * CDIM, CDIM, qb, kb, vb, nullptr);
    // attention: dual 128-row q-tiles; grid 256, 512 threads (r10 structure)
    attn_kernel<<<256, 512, 0, stream>>>(qb, kb, vb, aob);
    // proj: M=4096, N=1024, K=1024; 128x64 tiles, 256 thr; grid 512 (16 N x 32 M), CW=2
    gemm_nt_kernel<1, 128, 64, 4, 1, 2, 4, 16, 2><<<512, 256, 0, stream>>>(
        aob, pwb, MROWS, CDIM, CDIM, nullptr, nullptr, nullptr, proj_out);
}

// Round 14
// 94.998 us; speedup vs baseline: 1.1226x; 1.0382x over previous
//
#include <hip/hip_runtime.h>

// ---------- problem constants ----------
#define BB 4
#define WW 1024
#define CDIM 1024
#define CCH 32
#define NH 16
#define DH 64
#define MROWS (BB * WW)   // 4096

typedef __bf16 bf16x8 __attribute__((ext_vector_type(8)));
typedef float f32x4 __attribute__((ext_vector_type(4)));

static __device__ __forceinline__ unsigned short f2bf(float f) {
    union { float f; unsigned u; } v; v.f = f;
    unsigned r = v.u + 0x7fffu + ((v.u >> 16) & 1u);
    return (unsigned short)(r >> 16);
}

#if defined(__has_builtin)
#if __has_builtin(__builtin_amdgcn_global_load_lds)
#define HAVE_GLL 1
#endif
#endif

#ifdef HAVE_GLL
static __device__ __forceinline__ void gload16(const void* g, void* l) {
    __builtin_amdgcn_global_load_lds(
        (const __attribute__((address_space(1))) unsigned int*)g,
        (__attribute__((address_space(3))) unsigned int*)l, 16, 0, 0);
}
#endif

// ---------- kernel 1: fused weight-convert + pool (independent halves) ----------
__global__ __launch_bounds__(256) void prep_kernel(const float* __restrict__ aw,
                                                   const float* __restrict__ pw,
                                                   const float* __restrict__ x,
                                                   const float* __restrict__ pos,
                                                   const int* __restrict__ mask,
                                                   unsigned short* __restrict__ awb,
                                                   unsigned short* __restrict__ pwb,
                                                   float* __restrict__ word_f32,
                                                   unsigned short* __restrict__ word_bf) {
    int blk = blockIdx.x;
    if (blk < 4096) {
        int g = blk * 256 + threadIdx.x;          // 0 .. 1M-1
        const int NA4 = 3 * CDIM * CDIM / 4;      // 786432
        if (g < NA4) {
            float4 vv = ((const float4*)aw)[g];
            ushort4 o = { f2bf(vv.x), f2bf(vv.y), f2bf(vv.z), f2bf(vv.w) };
            ((ushort4*)awb)[g] = o;
        } else {
            int kk = g - NA4;
            float4 vv = ((const float4*)pw)[kk];
            ushort4 o = { f2bf(vv.x), f2bf(vv.y), f2bf(vv.z), f2bf(vv.w) };
            ((ushort4*)pwb)[kk] = o;
        }
    } else {
        int bw = blk - 4096;            // 0..4095
        int w = bw & (WW - 1);
        __shared__ int s_last;
        if (threadIdx.x == 0) {
            int ssum = 0;
            for (int j = 0; j < CCH; ++j) ssum += mask[bw * CCH + j];
            s_last = ssum - 1;          // may be -1 (one_hot(-1) == zeros)
        }
        __syncthreads();
        int last = s_last;
        const float4* xr = (const float4*)(x + ((size_t)bw * CCH + (last < 0 ? 0 : last)) * CDIM);
        const float4* pr = (const float4*)(pos + (size_t)w * CDIM);
        int d4 = threadIdx.x;
        float4 xv = (last >= 0) ? xr[d4] : float4{0.f, 0.f, 0.f, 0.f};
        float4 pv = pr[d4];
        float4 vv = { xv.x + pv.x, xv.y + pv.y, xv.z + pv.z, xv.w + pv.w };
        ((float4*)(word_f32 + (size_t)bw * CDIM))[d4] = vv;
        ushort4 o = { f2bf(vv.x), f2bf(vv.y), f2bf(vv.z), f2bf(vv.w) };
        ((ushort4*)(word_bf + (size_t)bw * CDIM))[d4] = o;
    }
}

// ---------- GEMM NT (m97 structure, 64KB-safe): C[m,n] = sum_k A[m,k]*Bt[n,k] ----------
// NW waves. 1D grid, XCD-aware decomposition (NBX N-tiles, CW = NBX/8 per XCD).
// Direct-store epilogue (r10-proven; LDS-restage variant measured -3us, reverted).
// EPI 0: scatter qkv (q scaled 0.125) bf16; EPI 1: f32 store to outp.
template <int EPI, int BM, int BN, int WRN, int WCN, int MI, int NI, int NBX, int CW>
__global__ __launch_bounds__(WRN * WCN * 64) void gemm_nt_kernel(
        const unsigned short* __restrict__ A,
        const unsigned short* __restrict__ Bt,
        int Mdim, int Ndim, int Kdim,
        unsigned short* __restrict__ qb,
        unsigned short* __restrict__ kb,
        unsigned short* __restrict__ vb,
        float* __restrict__ outp) {
    const int NW = WRN * WCN;
    const int NT = NW * 64;
    __shared__ unsigned short As[BM * 64];
    __shared__ unsigned short Bs[BN * 64];
    int t = threadIdx.x;
    int wid = t >> 6, lane = t & 63;
    int wr = wid / WCN, wc = wid % WCN;
    int bid = blockIdx.x;
    int xcd = bid & 7, idx = bid >> 3;
    int bx = xcd * CW + idx % CW;
    int by = idx / CW;
    int mbase = by * BM, nbase = bx * BN;
    int lr = lane & 15, lg = lane >> 4;
    f32x4 acc[MI][NI] = {};

#ifdef HAVE_GLL
    int csrc = ((lane & 7) ^ (lane >> 3)) * 8;   // pre-swizzled source column
    int rofs = lane >> 3;
    const int TOT = (BM + BN) / 8;               // 8-row chunks of 64 cols (1 KB each)
#endif

    for (int kt = 0; kt < Kdim; kt += 64) {
        __syncthreads();
#ifdef HAVE_GLL
        for (int cch = wid; cch < TOT; cch += NW) {
            if (cch < BM / 8)
                gload16(A + (size_t)(mbase + cch * 8 + rofs) * Kdim + kt + csrc, &As[cch * 8 * 64]);
            else {
                int cb = cch - BM / 8;
                gload16(Bt + (size_t)(nbase + cb * 8 + rofs) * Kdim + kt + csrc, &Bs[cb * 8 * 64]);
            }
        }
#else
        for (int s = 0; s < (BM + BN) * 8 / NT; ++s) {
            int f = s * NT + t;
            int row = f >> 3, c8 = (f & 7) * 8;
            if (row < BM)
                *(int4*)&As[row * 64 + (c8 ^ ((row & 7) << 3))] =
                    *(const int4*)&A[(size_t)(mbase + row) * Kdim + kt + c8];
            else {
                int rb = row - BM;
                *(int4*)&Bs[rb * 64 + (c8 ^ ((rb & 7) << 3))] =
                    *(const int4*)&Bt[(size_t)(nbase + rb) * Kdim + kt + c8];
            }
        }
#endif
        __syncthreads();
        for (int ks = 0; ks < 2; ++ks) {
            bf16x8 af[MI], bfr[NI];
            int cc = ks * 32 + lg * 8;
            for (int mi = 0; mi < MI; ++mi) {
                int r = wr * (MI * 16) + mi * 16 + lr;
                af[mi] = *(const bf16x8*)&As[r * 64 + (cc ^ ((r & 7) << 3))];
            }
            for (int ni = 0; ni < NI; ++ni) {
                int r = wc * (NI * 16) + ni * 16 + lr;
                bfr[ni] = *(const bf16x8*)&Bs[r * 64 + (cc ^ ((r & 7) << 3))];
            }
            __builtin_amdgcn_s_setprio(1);
            for (int mi = 0; mi < MI; ++mi)
                for (int ni = 0; ni < NI; ++ni)
                    acc[mi][ni] = __builtin_amdgcn_mfma_f32_16x16x32_bf16(af[mi], bfr[ni], acc[mi][ni], 0, 0, 0);
            __builtin_amdgcn_s_setprio(0);
        }
    }
    for (int mi = 0; mi < MI; ++mi)
        for (int ni = 0; ni < NI; ++ni)
            for (int i = 0; i < 4; ++i) {
                int row = mbase + wr * (MI * 16) + mi * 16 + lg * 4 + i;
                int col = nbase + wc * (NI * 16) + ni * 16 + lr;
                float v = acc[mi][ni][i];
                if (EPI == 0) {
                    int sect = col >> 10, ch = col & 1023, hh = ch >> 6, dd = ch & 63;
                    int bI = row >> 10, wI = row & 1023;
                    size_t dst = ((size_t)(bI * NH + hh) * WW + wI) * DH + dd;
                    if (sect == 0) qb[dst] = f2bf(v * 0.125f);
                    else if (sect == 1) kb[dst] = f2bf(v);
                    else vb[dst] = f2bf(v);
                } else {
                    outp[(size_t)row * Ndim + col] = v;
                }
            }
}

// ---------- kernel 4: causal flash attention (r10 structure, proven best) ----------
// 1D grid 256, 512 threads (8 waves, 16 rows per tile each). Block p handles
// q-tiles p and 7-p (18 kv-units). XCD remap co-locates a (b,h)'s 4 blocks.
// Static-shift softmax (no max-reduce, deferred row-sum); Ps wave-private.
__global__ __launch_bounds__(512) void attn_kernel(const unsigned short* __restrict__ q,
                                                   const unsigned short* __restrict__ k,
                                                   const unsigned short* __restrict__ v,
                                                   unsigned short* __restrict__ aout) {
    __shared__ unsigned short Ks[64 * 64];
    __shared__ unsigned short Vt[64 * 64];      // transposed: Vt[d][kv]
    __shared__ unsigned short Ps0[128 * 64];
    __shared__ unsigned short Ps1[128 * 64];
    int t = threadIdx.x;
    int wid = t >> 6, lane = t & 63;
    int lr = lane & 15, lg = lane >> 4;
    int bid = blockIdx.x;
    int xcd = bid & 7, idx = bid >> 3;          // idx 0..31
    int bh = xcd + ((idx >> 2) << 3);           // 0..63
    int p = idx & 3;                            // 0..3
    int bI = bh >> 4, hI = bh & 15;
    int qa = p * 128, qbv = (7 - p) * 128;
    int nktA = 2 * p + 2, nktB = 16 - 2 * p;
    const float EXP2C = 1.44269504f;             // log2(e)
    const float SHIFTC = 28.8539008f;            // 20 * log2(e)

    bf16x8 qfA[2], qfB[2];
    {
        const unsigned short* qg = q + (size_t)bh * WW * DH;
        int r = wid * 16 + lr;
        for (int ks = 0; ks < 2; ++ks) {
            qfA[ks] = *(const bf16x8*)&qg[(size_t)(qa + r) * DH + ks * 32 + lg * 8];
            qfB[ks] = *(const bf16x8*)&qg[(size_t)(qbv + r) * DH + ks * 32 + lg * 8];
        }
    }

    float rlA[4] = {0.f, 0.f, 0.f, 0.f}, rlB[4] = {0.f, 0.f, 0.f, 0.f};
    f32x4 oA[4] = {}, oB[4] = {};

    const unsigned short* kbase = k + (size_t)bh * WW * DH;
    const unsigned short* vbase = v + (size_t)bh * WW * DH;
    int dp = (t & 31) * 2, kb8 = (t >> 5) & 7;
    int tt = t & 255;
    int krow = tt >> 3, kc8 = (tt & 7) * 8;

    unsigned int vr[8]; int4 kr0, kr1;
    auto prefetch = [&](int tn) {
        if (wid < 4) {
            const unsigned short* vg = vbase + (size_t)tn * 64 * DH;
#pragma unroll
            for (int j = 0; j < 8; ++j)
                vr[j] = *(const unsigned int*)&vg[(size_t)(kb8 * 8 + j) * DH + dp];
        } else {
            const unsigned short* kg = kbase + (size_t)tn * 64 * DH;
            kr0 = *(const int4*)&kg[(size_t)krow * DH + kc8];
            kr1 = *(const int4*)&kg[(size_t)(krow + 32) * DH + kc8];
        }
    };
    prefetch(0);

    auto process = [&](const bf16x8* qf, const bf16x8 (*bfr)[4], int qbase,
                       float* rl, unsigned short* PsX, int tki) {
        f32x4 s[4] = {};
        __builtin_amdgcn_s_setprio(1);
#pragma unroll
        for (int ks = 0; ks < 2; ++ks)
#pragma unroll
            for (int ni = 0; ni < 4; ++ni)
                s[ni] = __builtin_amdgcn_mfma_f32_16x16x32_bf16(qf[ks], bfr[ks][ni], s[ni], 0, 0, 0);
        __builtin_amdgcn_s_setprio(0);
        int rowbase = qbase + wid * 16 + lg * 4;
        if (tki * 64 + 63 > qbase + wid * 16) {
            for (int ni = 0; ni < 4; ++ni)
                for (int i = 0; i < 4; ++i) {
                    int ki = tki * 64 + ni * 16 + lr;
                    if (ki > rowbase + i) s[ni][i] = -1e30f;
                }
        }
#pragma unroll
        for (int ni = 0; ni < 4; ++ni)
#pragma unroll
            for (int i = 0; i < 4; ++i) {
                float pe = __builtin_amdgcn_exp2f(fmaf(s[ni][i], EXP2C, -SHIFTC));
                s[ni][i] = pe;
                rl[i] += pe;
            }
        for (int ni = 0; ni < 4; ++ni)
            for (int i = 0; i < 4; ++i) {
                int r = wid * 16 + lg * 4 + i;
                PsX[r * 64 + ((ni * 16 + lr) ^ ((r & 7) << 3))] = f2bf(s[ni][i]);
            }
    };

    auto pvacc = [&](f32x4* o, const unsigned short* PsX, const bf16x8 (*vbf)[4]) {
#pragma unroll
        for (int ks = 0; ks < 2; ++ks) {
            int cc = ks * 32 + lg * 8;
            int r = wid * 16 + lr;
            bf16x8 pa = *(const bf16x8*)&PsX[r * 64 + (cc ^ ((r & 7) << 3))];
            __builtin_amdgcn_s_setprio(1);
#pragma unroll
            for (int di = 0; di < 4; ++di)
                o[di] = __builtin_amdgcn_mfma_f32_16x16x32_bf16(pa, vbf[ks][di], o[di], 0, 0, 0);
            __builtin_amdgcn_s_setprio(0);
        }
    };

    for (int tki = 0; tki < nktB; ++tki) {
        __syncthreads();   // prev iter's Ks/Vt reads complete
        if (wid < 4) {
            unsigned short lo[8], hi[8];
#pragma unroll
            for (int j = 0; j < 8; ++j) { lo[j] = (unsigned short)(vr[j] & 0xffffu);
                                          hi[j] = (unsigned short)(vr[j] >> 16); }
            *(int4*)&Vt[dp * 64 + ((kb8 * 8) ^ ((dp & 7) << 3))] = *(int4*)lo;
            int d1 = dp + 1;
            *(int4*)&Vt[d1 * 64 + ((kb8 * 8) ^ ((d1 & 7) << 3))] = *(int4*)hi;
        } else {
            *(int4*)&Ks[krow * 64 + (kc8 ^ ((krow & 7) << 3))] = kr0;
            int r1 = krow + 32;
            *(int4*)&Ks[r1 * 64 + (kc8 ^ ((r1 & 7) << 3))] = kr1;
        }
        if (tki + 1 < nktB) prefetch(tki + 1);   // loads fly under compute
        __syncthreads();

        bool wB = (tki * 64 <= qbv + wid * 16 + 15);   // wave-level diagonal skip
        bool wA = (tki < nktA) && (tki * 64 <= qa + wid * 16 + 15);

        bf16x8 bfr[2][4];                               // hoisted K-frags (shared)
#pragma unroll
        for (int ks = 0; ks < 2; ++ks) {
            int cc = ks * 32 + lg * 8;
#pragma unroll
            for (int ni = 0; ni < 4; ++ni) {
                int r = ni * 16 + lr;
                bfr[ks][ni] = *(const bf16x8*)&Ks[r * 64 + (cc ^ ((r & 7) << 3))];
            }
        }
        if (wB) process(qfB, bfr, qbv, rlB, Ps1, tki);
        if (wA) process(qfA, bfr, qa, rlA, Ps0, tki);

        bf16x8 vbf[2][4];                               // hoisted V-frags (shared)
#pragma unroll
        for (int ks = 0; ks < 2; ++ks) {
            int cc = ks * 32 + lg * 8;
#pragma unroll
            for (int di = 0; di < 4; ++di) {
                int rv = di * 16 + lr;
                vbf[ks][di] = *(const bf16x8*)&Vt[rv * 64 + (cc ^ ((rv & 7) << 3))];
            }
        }
        // no barrier: Ps rows are wave-private (written+read by the same wave)
        if (wB) pvacc(oB, Ps1, vbf);
        if (wA) pvacc(oA, Ps0, vbf);
    }

    // epilogue: one row-sum reduce + reciprocal per row, then store
    float riA[4], riB[4];
#pragma unroll
    for (int i = 0; i < 4; ++i) {
        for (int d = 8; d >= 1; d >>= 1) rlA[i] += __shfl_xor(rlA[i], d);
        for (int d = 8; d >= 1; d >>= 1) rlB[i] += __shfl_xor(rlB[i], d);
        riA[i] = 1.0f / rlA[i];
        riB[i] = 1.0f / rlB[i];
    }
    for (int di = 0; di < 4; ++di)
        for (int i = 0; i < 4; ++i) {
            int dd = di * 16 + lr;
            int qrA = qa + wid * 16 + lg * 4 + i;
            int qrB = qbv + wid * 16 + lg * 4 + i;
            aout[((size_t)bI * WW + qrA) * CDIM + hI * DH + dd] = f2bf(oA[di][i] * riA[i]);
            aout[((size_t)bI * WW + qrB) * CDIM + hI * DH + dd] = f2bf(oB[di][i] * riB[i]);
        }
}

// ---------- launch ----------
extern "C" void kernel_launch(void* const* d_in, const int* in_sizes, int n_in,
                              void* d_out, int out_size, void* d_ws, size_t ws_size,
                              hipStream_t stream) {
    const float* x    = (const float*)d_in[0];
    const float* pos  = (const float*)d_in[1];
    const float* aw   = (const float*)d_in[2];
    const float* pw   = (const float*)d_in[3];
    const int*   mask = (const int*)d_in[4];
    float* out = (float*)d_out;
    float* word_f32 = out;                        // [4096,1024] f32
    float* proj_out = out + (size_t)MROWS * CDIM; // [4096,1024] f32

    const size_t MB = 1u << 20;
    char* ws = (char*)d_ws;
    unsigned short* word_bf = (unsigned short*)(ws);             // 8 MB
    unsigned short* awb     = (unsigned short*)(ws + 8 * MB);    // 6 MB
    unsigned short* pwb     = (unsigned short*)(ws + 14 * MB);   // 2 MB
    unsigned short* qb      = (unsigned short*)(ws + 16 * MB);   // 8 MB
    unsigned short* kb      = (unsigned short*)(ws + 24 * MB);   // 8 MB
    unsigned short* vb      = (unsigned short*)(ws + 32 * MB);   // 8 MB
    unsigned short* aob     = (unsigned short*)(ws + 40 * MB);   // 8 MB

    prep_kernel<<<8192, 256, 0, stream>>>(aw, pw, x, pos, mask, awb, pwb, word_f32, word_bf);
    // QKV: M=4096, N=3072, K=1024; 128x128 tiles, 256 thr; grid 768 (24 N x 32 M), CW=3
    gemm_nt_kernel<0, 128, 128, 2, 2, 4, 4, 24, 3><<<768, 256, 0, stream>>>(
        word_bf, awb, MROWS, 3 * CDIM, CDIM, qb, kb, vb, nullptr);
    // attention: dual 128-row q-tiles; grid 256, 512 threads (r10 structure)
    attn_kernel<<<256, 512, 0, stream>>>(qb, kb, vb, aob);
    // proj: M=4096, N=1024, K=1024; 128x64 tiles, 256 thr; grid 512 (16 N x 32 M), CW=2
    gemm_nt_kernel<1, 128, 64, 4, 1, 2, 4, 16, 2><<<512, 256, 0, stream>>>(
        aob, pwb, MROWS, CDIM, CDIM, nullptr, nullptr, nullptr, proj_out);
}